// Round 3
// baseline (480.285 us; speedup 1.0000x reference)
//
#include <hip/hip_runtime.h>

// StyleWSConv as 9-position implicit GEMM, bf16 MFMA (16x16x32), fp32 accum.
// R3: 256co x 128px block (wave tile 128x64), register-pipelined A staging,
// fused prep (4 dispatches total).

#define EPSV   1e-8f
#define SCALEV 0.014731391274719738f  // 1/sqrt(512*9)

typedef __attribute__((ext_vector_type(8))) short short8;
typedef __attribute__((ext_vector_type(4))) float floatx4;

__device__ __forceinline__ void gload_lds16(const void* g, void* l) {
    __builtin_amdgcn_global_load_lds(
        (const __attribute__((address_space(1))) void*)g,
        (__attribute__((address_space(3))) void*)l, 16, 0, 0);
}

__device__ __forceinline__ unsigned short f2bf(float f) {
    unsigned u = __float_as_uint(f);
    unsigned r = (u + 0x7fffu + ((u >> 16) & 1u)) >> 16;
    return (unsigned short)r;
}

// ---------------- style inf-norm: t[b][ci] ----------------
__global__ __launch_bounds__(512) void prep_style(
    const float* __restrict__ style, float* __restrict__ tbuf)
{
    const int b = blockIdx.x, t = threadIdx.x;
    float v = style[b * 512 + t];
    __shared__ float red[512];
    red[t] = fabsf(v);
    __syncthreads();
    for (int s = 256; s > 0; s >>= 1) {
        if (t < s) red[t] = fmaxf(red[t], red[t + s]);
        __syncthreads();
    }
    tbuf[b * 512 + t] = v / red[0];
}

// ------- weights: wmax-normalize -> bf16 Aw[pos*16+cih][co][32ci]; g[b][co] -------
__global__ __launch_bounds__(256) void prep_w(
    const float* __restrict__ weight, const float* __restrict__ tbuf,
    unsigned short* __restrict__ Aw, float* __restrict__ gbuf)
{
    const int co = blockIdx.x, t = threadIdx.x;
    const float* wp = weight + (size_t)co * 4608;
    float m = 0.f;
    for (int i = t; i < 4608; i += 256) m = fmaxf(m, fabsf(wp[i]));
    __shared__ float red[256];
    red[t] = m;
    __syncthreads();
    for (int s = 128; s > 0; s >>= 1) {
        if (t < s) red[t] = fmaxf(red[t], red[t + s]);
        __syncthreads();
    }
    const float inv = 1.f / red[0];

    float sq[2];
    #pragma unroll
    for (int j = 0; j < 2; ++j) {
        int ci = t + j * 256;
        float s = 0.f;
        #pragma unroll
        for (int k = 0; k < 9; ++k) {
            float v = wp[ci * 9 + k] * inv;
            s = fmaf(v, v, s);
            Aw[(size_t)(k * 16 + (ci >> 5)) * 16384 + co * 32 + (ci & 31)] = f2bf(v);
        }
        sq[j] = s;
    }

    __shared__ float red8[8][256];
    #pragma unroll
    for (int bb = 0; bb < 8; ++bb) {
        float t0 = tbuf[bb * 512 + t], t1 = tbuf[bb * 512 + t + 256];
        red8[bb][t] = t0 * t0 * sq[0] + t1 * t1 * sq[1];
    }
    __syncthreads();
    for (int s = 128; s > 0; s >>= 1) {
        if (t < s) {
            #pragma unroll
            for (int bb = 0; bb < 8; ++bb) red8[bb][t] += red8[bb][t + s];
        }
        __syncthreads();
    }
    if (t < 8)
        gbuf[t * 512 + co] =
            SCALEV * SCALEV / sqrtf(fmaf(SCALEV * SCALEV, red8[t][0], EPSV));
}

// --- x -> padded NHWC bf16 with t folded: xbp[b][66][66][512]; borders fused ---
__global__ __launch_bounds__(256) void prep_x(
    const float* __restrict__ x, const float* __restrict__ tbuf,
    unsigned short* __restrict__ xbp)
{
    const int cic = blockIdx.x;  // 16 chunks of 32 ci
    const int h   = blockIdx.y;  // 64
    const int b   = blockIdx.z;  // 8
    const int tid = threadIdx.x;
    __shared__ float tr[64][33];

    const int cl = tid >> 3;
    const int w0 = (tid & 7) << 3;
    const int ci = cic * 32 + cl;
    const float tv = tbuf[b * 512 + ci];
    const float* xp = x + (((size_t)(b * 512 + ci)) << 12) + (h << 6) + w0;
    float4 u = *(const float4*)xp;
    float4 v = *(const float4*)(xp + 4);
    tr[w0 + 0][cl] = u.x * tv; tr[w0 + 1][cl] = u.y * tv;
    tr[w0 + 2][cl] = u.z * tv; tr[w0 + 3][cl] = u.w * tv;
    tr[w0 + 4][cl] = v.x * tv; tr[w0 + 5][cl] = v.y * tv;
    tr[w0 + 6][cl] = v.z * tv; tr[w0 + 7][cl] = v.w * tv;
    __syncthreads();

    const int w  = tid >> 2;
    const int c8 = (tid & 3) << 3;
    unsigned short o[8] __attribute__((aligned(16)));
    #pragma unroll
    for (int j = 0; j < 8; ++j) o[j] = f2bf(tr[w][c8 + j]);
    const size_t rowbase = ((size_t)(b * 66 + h + 1)) * 66 * 512 + cic * 32;
    *(uint4*)&xbp[rowbase + (size_t)(w + 1) * 512 + c8] = *(const uint4*)o;

    // zero borders (cols 0/65 of this row; rows 0/65 if edge block)
    uint4 z = {0u, 0u, 0u, 0u};
    if (tid < 8) {
        int colsel = (tid >> 2) ? 65 : 0;
        *(uint4*)&xbp[rowbase + (size_t)colsel * 512 + ((tid & 3) << 3)] = z;
    }
    if (h == 0 || h == 63) {
        const size_t rb = ((size_t)(b * 66) + (h ? 65 : 0)) * 66 * 512 + cic * 32;
        for (int i = tid; i < 264; i += 256)
            *(uint4*)&xbp[rb + (size_t)(i >> 2) * 512 + ((i & 3) << 3)] = z;
    }
}

// ---------------- main conv: 256co x 128px tile, pipelined A ----------------
// grid (32 px, 2 co, 8 b) = 512 blocks = 2/CU. 4 waves 2x2, wave = 128co x 64px.
__global__ __launch_bounds__(256, 2) void conv_mfma(
    const unsigned short* __restrict__ xbp, const unsigned short* __restrict__ Aw,
    const float* __restrict__ gbuf, const float* __restrict__ bias,
    const float* __restrict__ noise, const float* __restrict__ nstr,
    float* __restrict__ out)
{
    __shared__ __align__(16) short sA[16384];  // [2 half][256 co][32 ci] = 32 KB
    __shared__ __align__(16) short sB[13312];  // [2 half][208 px][32 ci] = 26 KB

    const int tid  = threadIdx.x;
    const int lane = tid & 63;
    const int wv   = tid >> 6;
    const int b    = blockIdx.z;
    const int co0  = blockIdx.y << 8;
    const int h0   = (blockIdx.x >> 1) << 2;
    const int w0   = (blockIdx.x & 1) << 5;

    const int n0  = lane & 15;
    const int kq  = lane >> 4;
    const int wco = (wv >> 1) << 7;  // 0 / 128
    const int wpx = (wv & 1) << 6;   // 0 / 64

    int prow[4], pcol[4];
    #pragma unroll
    for (int fj = 0; fj < 4; ++fj) {
        int p = wpx + fj * 16 + n0;
        prow[fj] = p >> 5;
        pcol[fj] = p & 31;
    }
    int aoff[8];
    #pragma unroll
    for (int fi = 0; fi < 8; ++fi) aoff[fi] = (wco + fi * 16 + n0) * 32 + kq * 8;

    const int sl_px = lane >> 2;
    const int sl_ci = (lane & 3) << 3;

    floatx4 zz = {0.f, 0.f, 0.f, 0.f};
    floatx4 acc[8][4];
    #pragma unroll
    for (int i = 0; i < 8; ++i)
        #pragma unroll
        for (int j = 0; j < 4; ++j) acc[i][j] = zz;

    const unsigned short* xb = xbp + (size_t)b * (4356 * 512);
    const unsigned short* awb = Aw + (co0 << 5);  // co0*32

    uint4 pf[8];
    #pragma unroll
    for (int c = 0; c < 8; ++c) {  // prologue: A[pos=0, ci0=0]
        int s = c * 2048 + tid * 8;
        pf[c] = *(const uint4*)&awb[(size_t)(s >> 13) * 16384 + (s & 8191)];
    }

    int pos = 0, cislab = 0;  // cislab = ci0>>5
    #pragma unroll 1
    for (int it = 0; it < 72; ++it) {
        __syncthreads();  // prior readers of sA (and sB when pos==0) done
        #pragma unroll
        for (int c = 0; c < 8; ++c)  // A regs -> LDS (vm wait hidden by prev MFMAs)
            *(uint4*)&sA[c * 2048 + tid * 8] = pf[c];
        if (pos == 0) {  // stage B tile for this ci0 (drained at next barrier)
            #pragma unroll
            for (int hf = 0; hf < 2; ++hf) {
                const unsigned short* src = xb + ((cislab + hf) << 5) + sl_ci;
                for (int j = wv; j < 13; j += 4) {
                    int px = j * 16 + sl_px;
                    if (px > 203) px = 203;
                    int row = px / 34, col = px - row * 34;
                    gload_lds16(src + (((size_t)(h0 + row) * 66 + w0 + col) << 9),
                                &sB[hf * 6656 + j * 512]);
                }
            }
        }
        __syncthreads();  // staged data visible
        if (it < 71) {    // issue next A prefetch; flies during MFMAs below
            int pn = pos + 1, cn = cislab;
            if (pn == 9) { pn = 0; cn += 2; }
            #pragma unroll
            for (int c = 0; c < 8; ++c) {
                int s = c * 2048 + tid * 8;
                pf[c] = *(const uint4*)
                    &awb[(size_t)(pn * 16 + cn + (s >> 13)) * 16384 + (s & 8191)];
            }
        }
        const int kh = pos / 3, kw = pos - kh * 3;
        #pragma unroll
        for (int hf = 0; hf < 2; ++hf) {
            short8 af[8], bfr[4];
            #pragma unroll
            for (int fi = 0; fi < 8; ++fi)
                af[fi] = *(const short8*)&sA[hf * 8192 + aoff[fi]];
            #pragma unroll
            for (int fj = 0; fj < 4; ++fj)
                bfr[fj] = *(const short8*)
                    &sB[hf * 6656 + ((prow[fj] + kh) * 34 + pcol[fj] + kw) * 32 + kq * 8];
            #pragma unroll
            for (int fi = 0; fi < 8; ++fi)
                #pragma unroll
                for (int fj = 0; fj < 4; ++fj)
                    acc[fi][fj] = __builtin_amdgcn_mfma_f32_16x16x32_bf16(
                        af[fi], bfr[fj], acc[fi][fj], 0, 0, 0);
        }
        if (++pos == 9) { pos = 0; cislab += 2; }
    }

    // epilogue: out = g*acc + bias + noise*ns
    const float ns = nstr[0];
    float nz[4];
    int ph[4], pw[4];
    #pragma unroll
    for (int fj = 0; fj < 4; ++fj) {
        int p = wpx + fj * 16 + n0;
        ph[fj] = h0 + (p >> 5);
        pw[fj] = w0 + (p & 31);
        nz[fj] = noise[(b << 12) + (ph[fj] << 6) + pw[fj]] * ns;
    }
    #pragma unroll
    for (int fi = 0; fi < 8; ++fi) {
        #pragma unroll
        for (int i = 0; i < 4; ++i) {
            int co = co0 + wco + fi * 16 + kq * 4 + i;
            float gg = gbuf[(b << 9) + co];
            float bb = bias[co];
            #pragma unroll
            for (int fj = 0; fj < 4; ++fj) {
                out[(((size_t)((b << 9) + co)) << 12) + (ph[fj] << 6) + pw[fj]] =
                    fmaf(gg, acc[fi][fj][i], bb + nz[fj]);
            }
        }
    }
}

extern "C" void kernel_launch(void* const* d_in, const int* in_sizes, int n_in,
                              void* d_out, int out_size, void* d_ws, size_t ws_size,
                              hipStream_t stream)
{
    const float* x      = (const float*)d_in[0];
    const float* style  = (const float*)d_in[1];
    const float* noise  = (const float*)d_in[2];
    const float* weight = (const float*)d_in[3];
    const float* bias   = (const float*)d_in[4];
    const float* nstr   = (const float*)d_in[5];
    float* out = (float*)d_out;
    char* ws = (char*)d_ws;

    // workspace layout (bytes)
    float*          tbuf = (float*)(ws);                    // 16384
    float*          gbuf = (float*)(ws + 16384);            // 16384
    unsigned short* Aw   = (unsigned short*)(ws + 32768);   // 4718592
    unsigned short* xbp  = (unsigned short*)(ws + 4751360); // 35684352 -> ~40.4 MB

    hipLaunchKernelGGL(prep_style, dim3(8), dim3(512), 0, stream, style, tbuf);
    hipLaunchKernelGGL(prep_w, dim3(512), dim3(256), 0, stream, weight, tbuf, Aw, gbuf);
    hipLaunchKernelGGL(prep_x, dim3(16, 64, 8), dim3(256), 0, stream, x, tbuf, xbp);
    hipLaunchKernelGGL(conv_mfma, dim3(32, 2, 8), dim3(256), 0, stream,
                       xbp, Aw, gbuf, bias, noise, nstr, out);
}

// Round 4
// 334.924 us; speedup vs baseline: 1.4340x; 1.4340x over previous
//
#include <hip/hip_runtime.h>

// StyleWSConv as 9-position implicit GEMM, bf16 MFMA (16x16x32), fp32 accum.
// R4: 128co x 128px block (wave 64x64, acc=64 VGPRs — no spill), A staged by
// global_load_lds into double-buffered LDS, B register-pipelined across slab
// boundary, Aw pre-swizzled + sB padded for conflict-free LDS reads.

#define EPSV   1e-8f
#define SCALEV 0.014731391274719738f  // 1/sqrt(512*9)

typedef __attribute__((ext_vector_type(8))) short short8;
typedef __attribute__((ext_vector_type(4))) float floatx4;

__device__ __forceinline__ void gload_lds16(const void* g, void* l) {
    __builtin_amdgcn_global_load_lds(
        (const __attribute__((address_space(1))) void*)g,
        (__attribute__((address_space(3))) void*)l, 16, 0, 0);
}

__device__ __forceinline__ unsigned short f2bf(float f) {
    unsigned u = __float_as_uint(f);
    unsigned r = (u + 0x7fffu + ((u >> 16) & 1u)) >> 16;
    return (unsigned short)r;
}

// =================== fused prep: weights part + x-transform part ===================
// grid (16, 64, 9): z<8 -> x-transform (cic=x, h=y, b=z); z==8, x<8 -> weights co=y*8+x
__global__ __launch_bounds__(256) void prep_all(
    const float* __restrict__ x, const float* __restrict__ style,
    const float* __restrict__ weight, unsigned short* __restrict__ Aw,
    unsigned short* __restrict__ xbp, float* __restrict__ gbuf)
{
    const int tid = threadIdx.x;
    __shared__ float red[256];

    if (blockIdx.z == 8) {
        if (blockIdx.x >= 8) return;
        const int co = blockIdx.y * 8 + blockIdx.x;
        const float* wp = weight + (size_t)co * 4608;
        __shared__ float sinv[8];
        __shared__ float red8[8][256];

        // per-sample style inv-max
        for (int b = 0; b < 8; ++b) {
            red[tid] = fmaxf(fabsf(style[b * 512 + tid]),
                             fabsf(style[b * 512 + tid + 256]));
            __syncthreads();
            for (int s = 128; s > 0; s >>= 1) {
                if (tid < s) red[tid] = fmaxf(red[tid], red[tid + s]);
                __syncthreads();
            }
            if (tid == 0) sinv[b] = 1.f / red[0];
            __syncthreads();
        }
        // per-filter inf-norm
        float m = 0.f;
        for (int i = tid; i < 4608; i += 256) m = fmaxf(m, fabsf(wp[i]));
        red[tid] = m;
        __syncthreads();
        for (int s = 128; s > 0; s >>= 1) {
            if (tid < s) red[tid] = fmaxf(red[tid], red[tid + s]);
            __syncthreads();
        }
        const float inv = 1.f / red[0];

        // Aw[pos*16+cih][co][32ci] with ci-chunk swizzle q' = (q + (co>>2)) & 3
        float sq[2];
        #pragma unroll
        for (int jj = 0; jj < 2; ++jj) {
            int ci = tid + jj * 256;
            int qs = (((ci >> 3) & 3) + (co >> 2)) & 3;
            float s = 0.f;
            #pragma unroll
            for (int k = 0; k < 9; ++k) {
                float v = wp[ci * 9 + k] * inv;
                s = fmaf(v, v, s);
                Aw[(size_t)(k * 16 + (ci >> 5)) * 16384 + co * 32 + (qs << 3) + (ci & 7)]
                    = f2bf(v);
            }
            sq[jj] = s;
        }
        // demod g[b][co]
        #pragma unroll
        for (int bb = 0; bb < 8; ++bb) {
            float t0 = style[bb * 512 + tid] * sinv[bb];
            float t1 = style[bb * 512 + tid + 256] * sinv[bb];
            red8[bb][tid] = t0 * t0 * sq[0] + t1 * t1 * sq[1];
        }
        __syncthreads();
        for (int s = 128; s > 0; s >>= 1) {
            if (tid < s) {
                #pragma unroll
                for (int bb = 0; bb < 8; ++bb) red8[bb][tid] += red8[bb][tid + s];
            }
            __syncthreads();
        }
        if (tid < 8)
            gbuf[tid * 512 + co] =
                SCALEV * SCALEV / sqrtf(fmaf(SCALEV * SCALEV, red8[tid][0], EPSV));
        return;
    }

    // ---- x -> padded NHWC bf16 with t folded: xbp[b][66][66][512] ----
    const int cic = blockIdx.x, h = blockIdx.y, b = blockIdx.z;
    __shared__ float tr[64][33];

    red[tid] = fmaxf(fabsf(style[b * 512 + tid]), fabsf(style[b * 512 + tid + 256]));
    __syncthreads();
    for (int s = 128; s > 0; s >>= 1) {
        if (tid < s) red[tid] = fmaxf(red[tid], red[tid + s]);
        __syncthreads();
    }
    const float inv = 1.f / red[0];

    const int cl = tid >> 3;
    const int w0 = (tid & 7) << 3;
    const int ci = cic * 32 + cl;
    const float tv = style[b * 512 + ci] * inv;
    const float* xp = x + (((size_t)(b * 512 + ci)) << 12) + (h << 6) + w0;
    float4 u = *(const float4*)xp;
    float4 v = *(const float4*)(xp + 4);
    tr[w0 + 0][cl] = u.x * tv; tr[w0 + 1][cl] = u.y * tv;
    tr[w0 + 2][cl] = u.z * tv; tr[w0 + 3][cl] = u.w * tv;
    tr[w0 + 4][cl] = v.x * tv; tr[w0 + 5][cl] = v.y * tv;
    tr[w0 + 6][cl] = v.z * tv; tr[w0 + 7][cl] = v.w * tv;
    __syncthreads();

    const int w  = tid >> 2;
    const int c8 = (tid & 3) << 3;
    unsigned short o[8] __attribute__((aligned(16)));
    #pragma unroll
    for (int j = 0; j < 8; ++j) o[j] = f2bf(tr[w][c8 + j]);
    const size_t rowbase = ((size_t)(b * 66 + h + 1)) * 66 * 512 + cic * 32;
    *(uint4*)&xbp[rowbase + (size_t)(w + 1) * 512 + c8] = *(const uint4*)o;

    uint4 z = {0u, 0u, 0u, 0u};
    if (tid < 8) {
        int colsel = (tid >> 2) ? 65 : 0;
        *(uint4*)&xbp[rowbase + (size_t)colsel * 512 + ((tid & 3) << 3)] = z;
    }
    if (h == 0 || h == 63) {
        const size_t rb = ((size_t)(b * 66) + (h ? 65 : 0)) * 66 * 512 + cic * 32;
        for (int i = tid; i < 264; i += 256)
            *(uint4*)&xbp[rb + (size_t)(i >> 2) * 512 + ((i & 3) << 3)] = z;
    }
}

// =================== main conv ===================
// grid (32 px, 4 co, 8 b) = 1024 blocks. 4 waves 2x2, wave tile 64co x 64px.
// sA double-buffered (DMA), sB single + register pipeline across slabs.
__global__ __launch_bounds__(256, 2) void conv_mfma(
    const unsigned short* __restrict__ xbp, const unsigned short* __restrict__ Aw,
    const float* __restrict__ gbuf, const float* __restrict__ bias,
    const float* __restrict__ noise, const float* __restrict__ nstr,
    float* __restrict__ out)
{
    __shared__ __align__(16) short sAs[16384];  // [2 dbuf][2 hf][128 co][32 ci] = 32 KB
    __shared__ __align__(16) short sBs[16320];  // [2 hf][204 px][40 pad]       = 32.6 KB

    const int tid  = threadIdx.x;
    const int lane = tid & 63;
    const int wv   = tid >> 6;
    const int b    = blockIdx.z;
    const int co0  = blockIdx.y << 7;
    const int h0   = (blockIdx.x >> 1) << 2;
    const int w0   = (blockIdx.x & 1) << 5;

    const int n0  = lane & 15;
    const int kq  = lane >> 4;
    const int wco = (wv >> 1) << 6;  // 0 / 64
    const int wpx = (wv & 1) << 6;   // 0 / 64

    int prow[4], pcol[4], aoff[4];
    #pragma unroll
    for (int fj = 0; fj < 4; ++fj) {
        int p = wpx + fj * 16 + n0;
        prow[fj] = p >> 5;
        pcol[fj] = p & 31;
    }
    const int qsw = (kq + (n0 >> 2)) & 3;  // matches prep Aw swizzle
    #pragma unroll
    for (int fi = 0; fi < 4; ++fi) aoff[fi] = (wco + fi * 16 + n0) * 32 + qsw * 8;

    // A-DMA decode: chunk c = (wv*4+j)*64 + lane; Aw short-offset (add P*16384)
    size_t aglo[4];
    #pragma unroll
    for (int j = 0; j < 4; ++j) {
        int c = (wv * 4 + j) * 64 + lane;
        aglo[j] = (size_t)(c >> 9) * 16384 + co0 * 32 + (c & 511) * 8;
    }

    // B slot decode: slot s covers [2 hf][204 px][4 q]
    int bg[7], boff[7];
    #pragma unroll
    for (int j = 0; j < 7; ++j) {
        int s = (j < 6) ? (j * 256 + tid) : (1536 + (tid < 96 ? tid : 95));
        int hf = s >= 816;
        int r  = s - hf * 816;
        int px = r >> 2;
        int q  = r & 3;
        int row = px / 34, col = px - row * 34;
        bg[j]   = ((h0 + row) * 66 + w0 + col) * 512 + hf * 32 + q * 8;
        boff[j] = hf * 8160 + px * 40 + q * 8;
    }

    const unsigned short* xb = xbp + (size_t)b * (4356 * 512);

    floatx4 zz = {0.f, 0.f, 0.f, 0.f};
    floatx4 acc[4][4];
    #pragma unroll
    for (int i = 0; i < 4; ++i)
        #pragma unroll
        for (int j = 0; j < 4; ++j) acc[i][j] = zz;

    uint4 Bpf[7];
    // prologue: B regs for slab 0; A DMA for it 0 into buf 0
    #pragma unroll
    for (int j = 0; j < 7; ++j)
        if (j < 6 || tid < 96) Bpf[j] = *(const uint4*)&xb[bg[j]];
    #pragma unroll
    for (int j = 0; j < 4; ++j)
        gload_lds16(Aw + aglo[j], &sAs[(wv * 4 + j) * 512]);

    int pos = 0, slab = 0;
    #pragma unroll 1
    for (int it = 0; it < 72; ++it) {
        const int cur = it & 1;
        __syncthreads();  // prefetch loads (issued last iter) done; old readers done
        if (pos == 0) {   // commit B regs -> LDS, make visible (lgkm-only drain)
            #pragma unroll
            for (int j = 0; j < 7; ++j)
                if (j < 6 || tid < 96) *(uint4*)&sBs[boff[j]] = Bpf[j];
            __syncthreads();
        }
        if (it < 71) {  // issue next-iter staging; retires during MFMAs below
            int np = pos + 1, ns = slab;
            if (np == 9) { np = 0; ++ns; }
            const unsigned short* asrc = Aw + (size_t)(np * 16 + ns * 2) * 16384;
            #pragma unroll
            for (int j = 0; j < 4; ++j)
                gload_lds16(asrc + aglo[j], &sAs[(cur ^ 1) * 8192 + (wv * 4 + j) * 512]);
            if (pos == 8) {
                const int cib = (slab + 1) * 64;
                #pragma unroll
                for (int j = 0; j < 7; ++j)
                    if (j < 6 || tid < 96) Bpf[j] = *(const uint4*)&xb[bg[j] + cib];
            }
        }
        const int kh = pos / 3, kw = pos - kh * 3;
        #pragma unroll
        for (int hf = 0; hf < 2; ++hf) {
            short8 af[4], bfr[4];
            #pragma unroll
            for (int fi = 0; fi < 4; ++fi)
                af[fi] = *(const short8*)&sAs[cur * 8192 + hf * 4096 + aoff[fi]];
            #pragma unroll
            for (int fj = 0; fj < 4; ++fj)
                bfr[fj] = *(const short8*)
                    &sBs[hf * 8160 + ((prow[fj] + kh) * 34 + pcol[fj] + kw) * 40 + kq * 8];
            #pragma unroll
            for (int fi = 0; fi < 4; ++fi)
                #pragma unroll
                for (int fj = 0; fj < 4; ++fj)
                    acc[fi][fj] = __builtin_amdgcn_mfma_f32_16x16x32_bf16(
                        af[fi], bfr[fj], acc[fi][fj], 0, 0, 0);
        }
        if (++pos == 9) { pos = 0; ++slab; }
    }

    // epilogue: out = g*acc + bias + noise*ns
    const float ns = nstr[0];
    float nz[4];
    int ph[4], pw[4];
    #pragma unroll
    for (int fj = 0; fj < 4; ++fj) {
        int p = wpx + fj * 16 + n0;
        ph[fj] = h0 + (p >> 5);
        pw[fj] = w0 + (p & 31);
        nz[fj] = noise[(b << 12) + (ph[fj] << 6) + pw[fj]] * ns;
    }
    #pragma unroll
    for (int fi = 0; fi < 4; ++fi) {
        #pragma unroll
        for (int i = 0; i < 4; ++i) {
            int co = co0 + wco + fi * 16 + kq * 4 + i;
            float gg = gbuf[(b << 9) + co];
            float bb = bias[co];
            #pragma unroll
            for (int fj = 0; fj < 4; ++fj) {
                out[(((size_t)((b << 9) + co)) << 12) + (ph[fj] << 6) + pw[fj]] =
                    fmaf(gg, acc[fi][fj][i], bb + nz[fj]);
            }
        }
    }
}

extern "C" void kernel_launch(void* const* d_in, const int* in_sizes, int n_in,
                              void* d_out, int out_size, void* d_ws, size_t ws_size,
                              hipStream_t stream)
{
    const float* x      = (const float*)d_in[0];
    const float* style  = (const float*)d_in[1];
    const float* noise  = (const float*)d_in[2];
    const float* weight = (const float*)d_in[3];
    const float* bias   = (const float*)d_in[4];
    const float* nstr   = (const float*)d_in[5];
    float* out = (float*)d_out;
    char* ws = (char*)d_ws;

    float*          gbuf = (float*)(ws);                    // 16384 B
    unsigned short* Aw   = (unsigned short*)(ws + 16384);   // 9,437,184 B (pos-major)
    unsigned short* xbp  = (unsigned short*)(ws + 16384 + 4718592);  // 35,684,352 B

    hipLaunchKernelGGL(prep_all, dim3(16, 64, 9), dim3(256), 0, stream,
                       x, style, weight, Aw, xbp, gbuf);
    hipLaunchKernelGGL(conv_mfma, dim3(32, 4, 8), dim3(256), 0, stream,
                       xbp, Aw, gbuf, bias, noise, nstr, out);
}